// Round 3
// baseline (686.196 us; speedup 1.0000x reference)
//
#include <hip/hip_runtime.h>

#define LTOT 13824          // 24*24*24
#define NCH 54              // scan chunks
#define CHL 256             // chunk length (54*256 = 13824)
#define EPSF 1e-5f

// ---------- workspace layout (floats) ----------
// [0..191]    branch IN sums        [192..383] branch IN sumsq
// [384..447]  final IN sum          [448..511] final IN sumsq
// [512..703]  branch mean           [704..895] branch rstd
// [896..959]  final mean            [960..1023] final rstd
static const size_t OFF_U   = 1024;                 // conv out, then LN in-place
static const size_t NU      = (size_t)3*LTOT*64;    // 2654208
static const size_t OFF_XI  = OFF_U  + NU;          // silu(conv1d(x)) ; later reused for FIN
static const size_t NXI     = (size_t)3*LTOT*128;   // 5308416
static const size_t OFF_SZ  = OFF_XI + NXI;         // silu(z) ; scan3 writes y in-place
static const size_t OFF_DT  = OFF_SZ + NXI;
static const size_t NBM     = (size_t)3*LTOT*16;    // 663552
static const size_t OFF_BM  = OFF_DT + NXI;
static const size_t OFF_CM  = OFF_BM + NBM;
static const size_t NAG     = (size_t)3*NCH*128*16; // 331776
static const size_t OFF_AGA = OFF_CM + NBM;
static const size_t OFF_AGB = OFF_AGA + NAG;
static const size_t OFF_SEED= OFF_AGB + NAG;
static const size_t OFF_W2  = OFF_SEED+ NAG;        // 384*64 = 24576
static const size_t OFF_FIN = OFF_XI;               // reuse xi region (dead after scan3)
// total = 20927488 floats ~ 80 MB

__device__ __forceinline__ float sigm(float x){ return 1.f/(1.f+__expf(-x)); }
__device__ __forceinline__ float siluf(float x){ return x*sigm(x); }
__device__ __forceinline__ float softplusf(float x){
    return fmaxf(x,0.f) + log1pf(__expf(-fabsf(x)));
}

// ================= K1: axis conv (k=3, 64->64) + IN stat partials ==========
// grid (576 rows, 3 branches), block 192 = 64 o * 3 w-groups of 8
__global__ void k_conv(const float* __restrict__ x,
                       const float* __restrict__ w1, const float* __restrict__ b1,
                       const float* __restrict__ w2, const float* __restrict__ b2,
                       const float* __restrict__ w3, const float* __restrict__ b3,
                       float* __restrict__ u, float* __restrict__ ws)
{
    __shared__ __align__(16) float xs[64*3*24];   // [(ic*3+t)*24 + w]  18432 B
    __shared__ float wl[96*64];                   // [k2*64 + o]        24576 B
    __shared__ float ssum[64], ssq[64];
    const int r = blockIdx.y;
    const int row = blockIdx.x;                   // d*24+h
    const int d = row/24, h = row%24;
    const float* W  = (r==0)?w1:(r==1)?w2:w3;
    const float* Bz = (r==0)?b1:(r==1)?b2:b3;
    const int tid = threadIdx.x;

    for (int s = tid; s < 4608; s += 192){
        int w = s % 24; int kt = s / 24; int ic = kt/3, t = kt%3;
        int src = 0; bool valid = true;
        if (r==0){ int dd = d+t-1; valid = (dd>=0 && dd<24); src = (dd*24+h)*24 + w; }
        else if (r==1){ int hh = h+t-1; valid = (hh>=0 && hh<24); src = (d*24+hh)*24 + w; }
        else { int ww = w+t-1; valid = (ww>=0 && ww<24); src = row*24 + ww; }
        xs[s] = valid ? x[(size_t)ic*LTOT + src] : 0.f;
    }
    if (tid < 64){ ssum[tid]=0.f; ssq[tid]=0.f; }

    const int o = tid & 63, wg = tid >> 6, w0 = wg*8;
    float bias = Bz[o];
    float acc[8];
    #pragma unroll
    for (int j=0;j<8;j++) acc[j]=bias;

    for (int half=0; half<2; half++){
        __syncthreads();
        for (int s = tid; s < 6144; s += 192){
            int o2 = s & 63, k2 = s >> 6;
            wl[k2*64 + o2] = W[(size_t)o2*192 + half*96 + k2];
        }
        __syncthreads();
        for (int ic2=0; ic2<32; ic2++){
            int ic = half*32 + ic2;
            #pragma unroll
            for (int t=0;t<3;t++){
                float wv = wl[(ic2*3+t)*64 + o];
                const float4* xp = (const float4*)&xs[(ic*3+t)*24 + w0];
                float4 a = xp[0], b = xp[1];
                acc[0]=fmaf(wv,a.x,acc[0]); acc[1]=fmaf(wv,a.y,acc[1]);
                acc[2]=fmaf(wv,a.z,acc[2]); acc[3]=fmaf(wv,a.w,acc[3]);
                acc[4]=fmaf(wv,b.x,acc[4]); acc[5]=fmaf(wv,b.y,acc[5]);
                acc[6]=fmaf(wv,b.z,acc[6]); acc[7]=fmaf(wv,b.w,acc[7]);
            }
        }
    }
    float ps=0.f, pq=0.f;
    size_t ub = ((size_t)r*LTOT + (size_t)row*24)*64;
    #pragma unroll
    for (int j=0;j<8;j++){
        float v = acc[j];
        u[ub + (size_t)(w0+j)*64 + o] = v;
        ps += v; pq += v*v;
    }
    atomicAdd(&ssum[o], ps); atomicAdd(&ssq[o], pq);
    __syncthreads();
    if (tid < 64){
        atomicAdd(&ws[r*64 + tid], ssum[tid]);
        atomicAdd(&ws[192 + r*64 + tid], ssq[tid]);
    }
}

// ================= K2: finalize branch IN stats ============================
__global__ void k_stats1(float* ws){
    int t = threadIdx.x;   // 0..191
    float s = ws[t], q = ws[192+t];
    float m = s*(1.f/(float)LTOT);
    float v = q*(1.f/(float)LTOT) - m*m;
    ws[512+t] = m; ws[704+t] = rsqrtf(v + EPSF);
}

// ================= K3: IN + ReLU + LayerNorm (in-place over u) =============
// grid (432, 3), block 256 (4 waves), wave = one position (lane = channel)
__global__ void k_inln(float* __restrict__ u, const float* __restrict__ ws,
                       const float* g1,const float* be1,const float* g2,const float* be2,
                       const float* g3,const float* be3,const float* lnw,const float* lnb)
{
    const int r = blockIdx.y;
    const int wv = threadIdx.x >> 6, c = threadIdx.x & 63;
    const float* g  = (r==0)?g1:(r==1)?g2:g3;
    const float* be = (r==0)?be1:(r==1)?be2:be3;
    float m  = ws[512 + r*64 + c], rs = ws[704 + r*64 + c];
    float gg = g[c], bb = be[c];
    float lw = lnw[c], lb = lnb[c];
    size_t base = (size_t)r*LTOT + (size_t)blockIdx.x*32 + wv*8;
    for (int p=0;p<8;p++){
        size_t idx = (base+p)*64 + c;
        float vv = fmaxf((u[idx]-m)*rs*gg + bb, 0.f);
        float s1 = vv, s2 = vv*vv;
        #pragma unroll
        for (int msk=1; msk<64; msk<<=1){
            s1 += __shfl_xor(s1, msk);
            s2 += __shfl_xor(s2, msk);
        }
        float mean = s1*(1.f/64.f);
        float var  = s2*(1.f/64.f) - mean*mean;
        u[idx] = (vv-mean)*rsqrtf(var+EPSF)*lw + lb;
    }
}

// ================= K4: in_proj + silu pointwise ============================
// grid (432, 3), block 256 (thread = output column j of 256)
__global__ void k_inproj(const float* __restrict__ xn, float* __restrict__ xi,
                         float* __restrict__ sz, const float* __restrict__ ipw,
                         const float* __restrict__ cw, const float* __restrict__ cb)
{
    __shared__ __align__(16) float xl[32*64];
    const int tid = threadIdx.x, r = blockIdx.y;
    size_t gbase = (size_t)r*LTOT + (size_t)blockIdx.x*32;
    for (int s = tid; s < 2048; s += 256) xl[s] = xn[gbase*64 + s];

    float wr[64];
    const float4* wp = (const float4*)(ipw + (size_t)tid*64);
    #pragma unroll
    for (int q=0;q<16;q++){
        float4 u4 = wp[q];
        wr[4*q]=u4.x; wr[4*q+1]=u4.y; wr[4*q+2]=u4.z; wr[4*q+3]=u4.w;
    }
    const bool isx = tid < 128;
    float ccw=0.f, ccb=0.f;
    if (isx){ ccw = cw[tid]; ccb = cb[tid]; }
    __syncthreads();

    for (int p=0;p<32;p++){
        const float4* xp = (const float4*)&xl[p*64];
        float a0=0,a1=0,a2=0,a3=0;
        #pragma unroll
        for (int q=0;q<16;q++){
            float4 a = xp[q];
            a0=fmaf(wr[4*q],a.x,a0); a1=fmaf(wr[4*q+1],a.y,a1);
            a2=fmaf(wr[4*q+2],a.z,a2); a3=fmaf(wr[4*q+3],a.w,a3);
        }
        float acc = (a0+a1)+(a2+a3);
        size_t gp = gbase + p;
        if (isx){
            float t = fmaf(acc, ccw, ccb);
            xi[gp*128 + tid] = siluf(t);
        } else {
            sz[gp*128 + (tid-128)] = siluf(acc);
        }
    }
}

// ================= K5: x_proj (36 dots) + dt softplus + B/C split ==========
// grid (432, 3), block 256 (4 waves), wave = 8 positions sequentially
__global__ void k_xproj(const float* __restrict__ xi, float* __restrict__ dt,
                        float* __restrict__ Bm, float* __restrict__ Cm,
                        const float* __restrict__ xpw, const float* __restrict__ dtw,
                        const float* __restrict__ dtb)
{
    const int wv = threadIdx.x >> 6, lane = threadIdx.x & 63;
    const int r = blockIdx.y;
    size_t base = (size_t)r*LTOT + (size_t)blockIdx.x*32 + wv*8;
    const int i0 = lane, i1 = lane+64;
    float4 dw0 = *(const float4*)(dtw + i0*4); float db0 = dtb[i0];
    float4 dw1 = *(const float4*)(dtw + i1*4); float db1 = dtb[i1];

    for (int p=0;p<8;p++){
        size_t gp = base + p;
        float x0 = xi[gp*128 + lane], x1 = xi[gp*128 + 64 + lane];
        float xv = 0.f;
        for (int k=0;k<36;k++){
            float w0 = xpw[k*128 + lane];
            float w1 = xpw[k*128 + 64 + lane];
            float pr = x0*w0 + x1*w1;
            #pragma unroll
            for (int msk=1; msk<64; msk<<=1) pr += __shfl_xor(pr, msk);
            xv = (lane==k) ? pr : xv;
        }
        if (lane>=4 && lane<20)       Bm[gp*16 + (lane-4)]  = xv;
        else if (lane>=20 && lane<36) Cm[gp*16 + (lane-20)] = xv;
        float d0=__shfl(xv,0), d1=__shfl(xv,1), d2=__shfl(xv,2), d3=__shfl(xv,3);
        float p0 = d0*dw0.x+d1*dw0.y+d2*dw0.z+d3*dw0.w+db0;
        float p1 = d0*dw1.x+d1*dw1.y+d2*dw1.z+d3*dw1.w+db1;
        dt[gp*128 + i0] = softplusf(p0);
        dt[gp*128 + i1] = softplusf(p1);
    }
}

// ================= K6: scan pass 1 — chunk aggregates ======================
// grid (54 chunks, 8 i-blocks, 3 branches), block 256: n = tid&15, i = ib*16 + tid>>4
__global__ void k_scan1(const float* __restrict__ dt, const float* __restrict__ Bm,
                        const float* __restrict__ xi, const float* __restrict__ Alog,
                        float* __restrict__ aga, float* __restrict__ agb)
{
    const int n = threadIdx.x & 15, il = threadIdx.x >> 4;
    const int c = blockIdx.x, ib = blockIdx.y, r = blockIdx.z;
    const int i = ib*16 + il;
    const float A = -expf(Alog[i*16+n]);
    const float* dtp = dt + (size_t)r*LTOT*128;
    const float* xip = xi + (size_t)r*LTOT*128;
    const float* bmp = Bm + (size_t)r*LTOT*16;
    float ap = 1.f, b = 0.f;
    const int lb = c*CHL;
    #pragma unroll 4
    for (int l=lb; l<lb+CHL; l++){
        float dtv = dtp[(size_t)l*128 + i];
        float xv  = xip[(size_t)l*128 + i];
        float bv  = bmp[(size_t)l*16 + n];
        float dA = __expf(A*dtv);
        ap *= dA;
        b = fmaf(dA, b, dtv*xv*bv);
    }
    size_t o = ((size_t)(r*NCH+c)*128 + i)*16 + n;
    aga[o] = ap; agb[o] = b;
}

// ================= K7: scan pass 2 — combine chunk aggregates ==============
// grid 12, block 512: thread = (r,i,n)
__global__ void k_scan2(const float* __restrict__ aga, const float* __restrict__ agb,
                        float* __restrict__ seed)
{
    int t = blockIdx.x*512 + threadIdx.x;  // 0..6143
    int r = t >> 11, rem = t & 2047;
    float h = 0.f;
    for (int c=0;c<NCH;c++){
        size_t idx = (size_t)(r*NCH+c)*2048 + rem;
        seed[idx] = h;
        h = fmaf(aga[idx], h, agb[idx]);
    }
}

// ================= K8: scan pass 3 — seeded replay + y (in-place into sz) ==
__global__ void k_scan3(const float* __restrict__ dt, const float* __restrict__ Bm,
                        const float* __restrict__ Cm, const float* __restrict__ xi,
                        float* __restrict__ szy, const float* __restrict__ Alog,
                        const float* __restrict__ Dp, const float* __restrict__ seed)
{
    const int n = threadIdx.x & 15, il = threadIdx.x >> 4;
    const int c = blockIdx.x, ib = blockIdx.y, r = blockIdx.z;
    const int i = ib*16 + il;
    const float A = -expf(Alog[i*16+n]);
    const float Dv = Dp[i];
    const float* dtp = dt + (size_t)r*LTOT*128;
    const float* xip = xi + (size_t)r*LTOT*128;
    const float* bmp = Bm + (size_t)r*LTOT*16;
    const float* cmp = Cm + (size_t)r*LTOT*16;
    float* szp = szy + (size_t)r*LTOT*128;

    float h = seed[(size_t)(r*NCH+c)*2048 + (i*16+n)];
    const int lb = c*CHL;
    #pragma unroll 2
    for (int l=lb; l<lb+CHL; l++){
        float dtv = dtp[(size_t)l*128 + i];
        float xv  = xip[(size_t)l*128 + i];
        float bv  = bmp[(size_t)l*16 + n];
        float cv  = cmp[(size_t)l*16 + n];
        float dA = __expf(A*dtv);
        h = fmaf(dA, h, dtv*xv*bv);
        float py = h*cv;
        py += __shfl_xor(py, 1);
        py += __shfl_xor(py, 2);
        py += __shfl_xor(py, 4);
        py += __shfl_xor(py, 8);
        if (n==0){
            size_t yi = (size_t)l*128 + i;
            szp[yi] = (py + xv*Dv) * szp[yi];   // sz holds silu(z); in-place y
        }
    }
}

// ================= K9: fuse out_proj with final 1x1 conv weights ===========
// W2T[(r*128+i)*64 + o] = sum_c opw[c*128+i] * wf[o*192 + r*64 + c]
__global__ void k_w2(const float* __restrict__ opw, const float* __restrict__ wf,
                     float* __restrict__ w2t)
{
    int idx = blockIdx.x*256 + threadIdx.x;  // 0..24575
    int o = idx & 63, ri = idx >> 6;
    int r = ri >> 7, i = ri & 127;
    float acc = 0.f;
    for (int c2=0;c2<64;c2++)
        acc += opw[c2*128+i] * wf[o*192 + r*64 + c2];
    w2t[idx] = acc;
}

// ================= K10: fused out_proj + final conv (GEMM) + IN partials ===
// grid 864, block 256 = 64 o * 4 subgroups (each 4 positions); 16 pos/block
__global__ void k_fin(const float* __restrict__ y, const float* __restrict__ w2t,
                      const float* __restrict__ bfb, float* __restrict__ fin,
                      float* __restrict__ ws)
{
    __shared__ float yl[16*384];
    __shared__ float wt[64*64];
    __shared__ float ssum[64], ssq[64];
    const int tid = threadIdx.x;
    const int l0 = blockIdx.x*16;
    for (int s=tid; s<16*384; s+=256){
        int p = s/384, k = s%384, r = k>>7, i = k&127;
        yl[s] = y[((size_t)r*LTOT + l0 + p)*128 + i];
    }
    if (tid<64){ ssum[tid]=0.f; ssq[tid]=0.f; }
    const int o = tid & 63, sg = tid >> 6;
    float bias = bfb[o];
    float acc[4];
    #pragma unroll
    for (int j=0;j<4;j++) acc[j]=bias;

    for (int kt=0; kt<6; kt++){
        __syncthreads();
        for (int s=tid; s<4096; s+=256){
            int kl = s>>6, oo = s&63;
            wt[kl*64+oo] = w2t[(size_t)(kt*64+kl)*64 + oo];
        }
        __syncthreads();
        for (int kl=0; kl<64; kl++){
            float wv = wt[kl*64+o];
            int k = kt*64+kl;
            #pragma unroll
            for (int j=0;j<4;j++)
                acc[j] = fmaf(wv, yl[(sg*4+j)*384 + k], acc[j]);
        }
    }
    float ps=0.f, pq=0.f;
    #pragma unroll
    for (int j=0;j<4;j++){
        float v = acc[j];
        fin[(size_t)(l0+sg*4+j)*64 + o] = v;
        ps += v; pq += v*v;
    }
    atomicAdd(&ssum[o], ps); atomicAdd(&ssq[o], pq);
    __syncthreads();
    if (tid<64){
        atomicAdd(&ws[384+tid], ssum[tid]);
        atomicAdd(&ws[448+tid], ssq[tid]);
    }
}

// ================= K11: finalize final IN stats ============================
__global__ void k_statsF(float* ws){
    int t = threadIdx.x;  // 0..63
    float s = ws[384+t], q = ws[448+t];
    float m = s*(1.f/(float)LTOT);
    float v = q*(1.f/(float)LTOT) - m*m;
    ws[896+t] = m; ws[960+t] = rsqrtf(v + EPSF);
}

// ================= K12: final IN + ReLU + transpose + fp32 store ===========
// grid 216, block 256: tile of 64 positions x 64 channels
__global__ void k_out(const float* __restrict__ fin, const float* __restrict__ ws,
                      const float* __restrict__ gf, const float* __restrict__ bef,
                      float* __restrict__ out)
{
    __shared__ float tl[64*65];
    const int tid = threadIdx.x;
    const int l0 = blockIdx.x*64;
    for (int s=tid; s<4096; s+=256){
        int li = s>>6, o = s&63;
        float v = fin[(size_t)(l0+li)*64 + o];
        v = fmaxf((v - ws[896+o])*ws[960+o]*gf[o] + bef[o], 0.f);
        tl[o*65+li] = v;
    }
    __syncthreads();
    for (int s=tid; s<4096; s+=256){
        int o = s>>6, li = s&63;
        out[(size_t)o*LTOT + l0 + li] = tl[o*65+li];
    }
}

extern "C" void kernel_launch(void* const* d_in, const int* in_sizes, int n_in,
                              void* d_out, int out_size, void* d_ws, size_t ws_size,
                              hipStream_t stream)
{
    const float* X    = (const float*)d_in[0];
    const float* W1   = (const float*)d_in[1];  const float* B1  = (const float*)d_in[2];
    const float* G1   = (const float*)d_in[3];  const float* BE1 = (const float*)d_in[4];
    const float* W2   = (const float*)d_in[5];  const float* B2  = (const float*)d_in[6];
    const float* G2   = (const float*)d_in[7];  const float* BE2 = (const float*)d_in[8];
    const float* W3   = (const float*)d_in[9];  const float* B3  = (const float*)d_in[10];
    const float* G3   = (const float*)d_in[11]; const float* BE3 = (const float*)d_in[12];
    const float* LNW  = (const float*)d_in[13]; const float* LNB = (const float*)d_in[14];
    const float* IPW  = (const float*)d_in[15];
    const float* CW   = (const float*)d_in[16]; const float* CB  = (const float*)d_in[17];
    const float* XPW  = (const float*)d_in[18];
    const float* DTW  = (const float*)d_in[19]; const float* DTB = (const float*)d_in[20];
    const float* ALOG = (const float*)d_in[21]; const float* DP  = (const float*)d_in[22];
    const float* OPW  = (const float*)d_in[23];
    const float* WF   = (const float*)d_in[24]; const float* BF  = (const float*)d_in[25];
    const float* GF   = (const float*)d_in[26]; const float* BEF = (const float*)d_in[27];
    float* ws = (float*)d_ws;

    // zero stat accumulators (first 512 floats)
    (void)hipMemsetAsync(d_ws, 0, 2048, stream);

    k_conv  <<<dim3(576,3), 192, 0, stream>>>(X, W1,B1, W2,B2, W3,B3, ws+OFF_U, ws);
    k_stats1<<<1, 192, 0, stream>>>(ws);
    k_inln  <<<dim3(432,3), 256, 0, stream>>>(ws+OFF_U, ws,
                                              G1,BE1,G2,BE2,G3,BE3, LNW,LNB);
    k_inproj<<<dim3(432,3), 256, 0, stream>>>(ws+OFF_U, ws+OFF_XI, ws+OFF_SZ,
                                              IPW, CW, CB);
    k_xproj <<<dim3(432,3), 256, 0, stream>>>(ws+OFF_XI, ws+OFF_DT, ws+OFF_BM,
                                              ws+OFF_CM, XPW, DTW, DTB);
    k_scan1 <<<dim3(NCH,8,3), 256, 0, stream>>>(ws+OFF_DT, ws+OFF_BM, ws+OFF_XI,
                                                ALOG, ws+OFF_AGA, ws+OFF_AGB);
    k_scan2 <<<12, 512, 0, stream>>>(ws+OFF_AGA, ws+OFF_AGB, ws+OFF_SEED);
    k_scan3 <<<dim3(NCH,8,3), 256, 0, stream>>>(ws+OFF_DT, ws+OFF_BM, ws+OFF_CM,
                                                ws+OFF_XI, ws+OFF_SZ, ALOG, DP,
                                                ws+OFF_SEED);
    k_w2    <<<96, 256, 0, stream>>>(OPW, WF, ws+OFF_W2);
    k_fin   <<<864, 256, 0, stream>>>(ws+OFF_SZ, ws+OFF_W2, BF, ws+OFF_FIN, ws);
    k_statsF<<<1, 64, 0, stream>>>(ws);
    k_out   <<<216, 256, 0, stream>>>(ws+OFF_FIN, ws, GF, BEF, (float*)d_out);
}